// Round 3
// baseline (187.791 us; speedup 1.0000x reference)
//
#include <hip/hip_runtime.h>

// BAD descriptor: integral image + clamped box-mean differences.
// B=2, H=W=224, P=256, max_radius=3.
#define BN 2
#define HN 224
#define WN 224
#define PN 256
#define RN 3
#define IW 231          // H + 2*R + 1  (integral has a zero top row / left col)
#define ISZ (IW * IW)
#define NPIX (HN * WN)  // 50176

// One wave per integral row (wave-shuffle inclusive scan over 4 chunks of 64).
__global__ __launch_bounds__(256) void integral_rows_kernel(
    const float* __restrict__ x, float* __restrict__ I)
{
    const int wave = (blockIdx.x * 256 + threadIdx.x) >> 6;
    const int lane = threadIdx.x & 63;
    if (wave >= BN * IW) return;
    const int b = wave / IW, i = wave % IW;
    float* Ib = I + b * ISZ + i * IW;
    if (i == 0) {   // zero top row
        for (int j = lane; j < IW; j += 64) Ib[j] = 0.0f;
        return;
    }
    int yy = i - 1 - RN;
    yy = yy < 0 ? 0 : (yy > HN - 1 ? HN - 1 : yy);
    const float* xr = x + b * HN * WN + yy * WN;

    float carry = 0.0f;
#pragma unroll
    for (int c = 0; c < 4; ++c) {           // 4*64 = 256 >= 231
        const int j = c * 64 + lane;
        float v = 0.0f;
        if (j >= 1 && j < IW) {
            int xx = j - 1 - RN;
            xx = xx < 0 ? 0 : (xx > WN - 1 ? WN - 1 : xx);
            v = xr[xx];
        }
#pragma unroll
        for (int d = 1; d < 64; d <<= 1) {
            float n = __shfl_up(v, d, 64);
            if (lane >= d) v += n;
        }
        v += carry;
        if (j < IW) Ib[j] = v;
        carry = __shfl(v, 63, 64);
    }
}

// Thread per (batch, column); coalesced loads/stores down the rows.
__global__ __launch_bounds__(256) void integral_cols_kernel(float* __restrict__ I)
{
    const int t = blockIdx.x * 256 + threadIdx.x;
    if (t >= BN * IW) return;
    const int b = t / IW, j = t % IW;
    float* Ib = I + b * ISZ;
    float acc = 0.0f;
#pragma unroll 11
    for (int i = 1; i < IW; ++i) {
        acc += Ib[i * IW + j];
        Ib[i * IW + j] = acc;
    }
}

// Block = (64,4): lanes = 64-wide x-tile (y wave-uniform), 4 waves = 4 rows.
// y uniform per wave -> readfirstlane the clamped row indices -> row base
// pointers live in SGPRs -> all 8 gathers + store use saddr form (scalar base
// + per-lane byte offset), eliminating per-gather 64-bit VALU address math.
__global__ __launch_bounds__(256) void bad_main_kernel(
    const float* __restrict__ I,
    const float* __restrict__ ox1, const float* __restrict__ ox2,
    const float* __restrict__ oy1, const float* __restrict__ oy2,
    const int*   __restrict__ radii, const float* __restrict__ thr,
    float* __restrict__ out)
{
    const int p  = blockIdx.y;
    const int b  = blockIdx.z;
    const int xt = blockIdx.x & 3;          // 4 x-tiles of 64 (tile 3 half-masked)
    const int yt = blockIdx.x >> 2;         // 56 y-tiles of 4 rows
    const int x  = xt * 64 + threadIdx.x;   // threadIdx.x in 0..63
    const int y  = yt * 4 + threadIdx.y;    // wave-uniform (blockDim.x == 64)

    // block-uniform descriptor params -> scalar loads
    const float offx1 = ox1[p], offx2 = ox2[p];
    const float offy1 = oy1[p], offy2 = oy2[p];
    const int   rad   = radii[p];
    const float t     = thr[p];
    const float side  = (float)(2 * rad + 1);
    const float inv_area = 1.0f / (side * side);

    const float* Ib = I + b * ISZ;

    // per-thread x chains (computed once; clamp keeps masked lanes in-bounds)
    const float fx = (float)x;
    const int cx1 = (int)fminf(fmaxf(fx + offx1, 0.0f), (float)(WN - 1)) + RN;
    const int a0 = cx1 - rad, a1 = cx1 + rad + 1;
    const int cx2 = (int)fminf(fmaxf(fx + offx2, 0.0f), (float)(WN - 1)) + RN;
    const int b0 = cx2 - rad, b1 = cx2 + rad + 1;

    // wave-uniform y chains -> force scalar row bases
    const float fy = (float)y;
    const int cy1 = __builtin_amdgcn_readfirstlane(
                        (int)fminf(fmaxf(fy + offy1, 0.0f), (float)(HN - 1))) + RN;
    const int cy2 = __builtin_amdgcn_readfirstlane(
                        (int)fminf(fmaxf(fy + offy2, 0.0f), (float)(HN - 1))) + RN;
    const float* r1lo = Ib + (cy1 - rad) * IW;
    const float* r1hi = Ib + (cy1 + rad + 1) * IW;
    const float* r2lo = Ib + (cy2 - rad) * IW;
    const float* r2hi = Ib + (cy2 + rad + 1) * IW;

    const float s1 = r1hi[a1] - r1lo[a1] - r1hi[a0] + r1lo[a0];
    const float s2 = r2hi[b1] - r2lo[b1] - r2hi[b0] + r2lo[b0];

    if (x < WN) {
        float* outrow = out + (b * PN + p) * NPIX + y * WN;   // scalar base
        outrow[x] = (s1 - s2) * inv_area - t;
    }
}

extern "C" void kernel_launch(void* const* d_in, const int* in_sizes, int n_in,
                              void* d_out, int out_size, void* d_ws, size_t ws_size,
                              hipStream_t stream)
{
    const float* x    = (const float*)d_in[0];
    const float* ox1  = (const float*)d_in[1];
    const float* ox2  = (const float*)d_in[2];
    const float* oy1  = (const float*)d_in[3];
    const float* oy2  = (const float*)d_in[4];
    const int*   rad  = (const int*)d_in[5];
    const float* thr  = (const float*)d_in[6];

    float* I   = (float*)d_ws;            // BN*ISZ floats = ~427 KB
    float* out = (float*)d_out;

    hipLaunchKernelGGL(integral_rows_kernel, dim3((BN * IW * 64 + 255) / 256), dim3(256), 0, stream, x, I);
    hipLaunchKernelGGL(integral_cols_kernel, dim3((BN * IW + 255) / 256), dim3(256), 0, stream, I);
    hipLaunchKernelGGL(bad_main_kernel,      dim3(4 * 56, PN, BN), dim3(64, 4, 1), 0, stream,
                       I, ox1, ox2, oy1, oy2, rad, thr, out);
}

// Round 4
// 161.620 us; speedup vs baseline: 1.1619x; 1.1619x over previous
//
#include <hip/hip_runtime.h>

// BAD descriptor: integral image + clamped box-mean differences.
// B=2, H=W=224, P=256, max_radius=3.
#define BN 2
#define HN 224
#define WN 224
#define PN 256
#define RN 3
#define IW 231          // H + 2*R + 1  (integral has a zero top row / left col)
#define ISZ (IW * IW)
#define NPIX (HN * WN)  // 50176

// One wave per integral row (wave-shuffle inclusive scan over 4 chunks of 64).
__global__ __launch_bounds__(256) void integral_rows_kernel(
    const float* __restrict__ x, float* __restrict__ I)
{
    const int wave = (blockIdx.x * 256 + threadIdx.x) >> 6;
    const int lane = threadIdx.x & 63;
    if (wave >= BN * IW) return;
    const int b = wave / IW, i = wave % IW;
    float* Ib = I + b * ISZ + i * IW;
    if (i == 0) {   // zero top row
        for (int j = lane; j < IW; j += 64) Ib[j] = 0.0f;
        return;
    }
    int yy = i - 1 - RN;
    yy = yy < 0 ? 0 : (yy > HN - 1 ? HN - 1 : yy);
    const float* xr = x + b * HN * WN + yy * WN;

    float carry = 0.0f;
#pragma unroll
    for (int c = 0; c < 4; ++c) {           // 4*64 = 256 >= 231
        const int j = c * 64 + lane;
        float v = 0.0f;
        if (j >= 1 && j < IW) {
            int xx = j - 1 - RN;
            xx = xx < 0 ? 0 : (xx > WN - 1 ? WN - 1 : xx);
            v = xr[xx];
        }
#pragma unroll
        for (int d = 1; d < 64; d <<= 1) {
            float n = __shfl_up(v, d, 64);
            if (lane >= d) v += n;
        }
        v += carry;
        if (j < IW) Ib[j] = v;
        carry = __shfl(v, 63, 64);
    }
}

// Thread per (batch, column); coalesced loads/stores down the rows.
__global__ __launch_bounds__(256) void integral_cols_kernel(float* __restrict__ I)
{
    const int t = blockIdx.x * 256 + threadIdx.x;
    if (t >= BN * IW) return;
    const int b = t / IW, j = t % IW;
    float* Ib = I + b * ISZ;
    float acc = 0.0f;
#pragma unroll 11
    for (int i = 1; i < IW; ++i) {
        acc += Ib[i * IW + j];
        Ib[i * IW + j] = acc;
    }
}

// Block (64,4): lanes = 64-wide x-tile; each wave loops over 28 rows (y-step 4).
// x-chains (clamps + the 4 gather column offsets) computed ONCE per thread and
// reused across all rows; per-row work is the wave-uniform y-chain
// (readfirstlane -> SALU row pointers), 8 saddr gathers, 7 float ops, 1 store.
__global__ __launch_bounds__(256) void bad_main_kernel(
    const float* __restrict__ I,
    const float* __restrict__ ox1, const float* __restrict__ ox2,
    const float* __restrict__ oy1, const float* __restrict__ oy2,
    const int*   __restrict__ radii, const float* __restrict__ thr,
    float* __restrict__ out)
{
    const int p  = blockIdx.y;
    const int b  = blockIdx.z;
    const int xt = blockIdx.x & 3;              // 4 x-tiles of 64 (tile 3 part-masked)
    const int yt = blockIdx.x >> 2;             // 2 y-halves of 112 rows
    const int x  = xt * 64 + threadIdx.x;       // threadIdx.x in 0..63
    const int y0 = yt * (HN / 2) + threadIdx.y; // wave-uniform start row

    // block-uniform descriptor params -> scalar loads
    const float offx1 = ox1[p], offx2 = ox2[p];
    const float offy1 = oy1[p], offy2 = oy2[p];
    const int   rad   = radii[p];
    const float t     = thr[p];
    const float side  = (float)(2 * rad + 1);
    const float inv_area = 1.0f / (side * side);

    const float* Ib = I + b * ISZ;

    // per-thread x chains, computed once (clamp keeps masked lanes in-bounds)
    const float fx = (float)x;
    const int cx1 = (int)fminf(fmaxf(fx + offx1, 0.0f), (float)(WN - 1)) + RN;
    const int a0 = cx1 - rad, a1 = cx1 + rad + 1;
    const int cx2 = (int)fminf(fmaxf(fx + offx2, 0.0f), (float)(WN - 1)) + RN;
    const int b0 = cx2 - rad, b1 = cx2 + rad + 1;

    const bool xok = (x < WN);
    float* outp = out + (size_t)(b * PN + p) * NPIX + (size_t)y0 * WN;

#pragma unroll 4
    for (int i = 0; i < HN / 2; i += 4) {
        const int y = y0 + i;
        const float fy = (float)y;
        const int cy1 = __builtin_amdgcn_readfirstlane(
                            (int)fminf(fmaxf(fy + offy1, 0.0f), (float)(HN - 1))) + RN;
        const int cy2 = __builtin_amdgcn_readfirstlane(
                            (int)fminf(fmaxf(fy + offy2, 0.0f), (float)(HN - 1))) + RN;
        const float* r1lo = Ib + (cy1 - rad) * IW;
        const float* r1hi = Ib + (cy1 + rad + 1) * IW;
        const float* r2lo = Ib + (cy2 - rad) * IW;
        const float* r2hi = Ib + (cy2 + rad + 1) * IW;

        const float s1 = r1hi[a1] - r1lo[a1] - r1hi[a0] + r1lo[a0];
        const float s2 = r2hi[b1] - r2lo[b1] - r2hi[b0] + r2lo[b0];

        if (xok) outp[i * WN + x] = (s1 - s2) * inv_area - t;
    }
}

extern "C" void kernel_launch(void* const* d_in, const int* in_sizes, int n_in,
                              void* d_out, int out_size, void* d_ws, size_t ws_size,
                              hipStream_t stream)
{
    const float* x    = (const float*)d_in[0];
    const float* ox1  = (const float*)d_in[1];
    const float* ox2  = (const float*)d_in[2];
    const float* oy1  = (const float*)d_in[3];
    const float* oy2  = (const float*)d_in[4];
    const int*   rad  = (const int*)d_in[5];
    const float* thr  = (const float*)d_in[6];

    float* I   = (float*)d_ws;            // BN*ISZ floats = ~427 KB
    float* out = (float*)d_out;

    hipLaunchKernelGGL(integral_rows_kernel, dim3((BN * IW * 64 + 255) / 256), dim3(256), 0, stream, x, I);
    hipLaunchKernelGGL(integral_cols_kernel, dim3((BN * IW + 255) / 256), dim3(256), 0, stream, I);
    hipLaunchKernelGGL(bad_main_kernel,      dim3(8, PN, BN), dim3(64, 4, 1), 0, stream,
                       I, ox1, ox2, oy1, oy2, rad, thr, out);
}

// Round 5
// 148.498 us; speedup vs baseline: 1.2646x; 1.0884x over previous
//
#include <hip/hip_runtime.h>

// BAD descriptor: integral image + per-radius box-mean maps + 2-gather main.
// B=2, H=W=224, P=256, max_radius=3, radii in {1,2,3}.
#define BN 2
#define HN 224
#define WN 224
#define PN 256
#define RN 3
#define IW 231          // H + 2*R + 1  (integral has a zero top row / left col)
#define ISZ (IW * IW)
#define NPIX (HN * WN)  // 50176

// One wave per integral row (wave-shuffle inclusive scan over 4 chunks of 64).
__global__ __launch_bounds__(256) void integral_rows_kernel(
    const float* __restrict__ x, float* __restrict__ I)
{
    const int wave = (blockIdx.x * 256 + threadIdx.x) >> 6;
    const int lane = threadIdx.x & 63;
    if (wave >= BN * IW) return;
    const int b = wave / IW, i = wave % IW;
    float* Ib = I + b * ISZ + i * IW;
    if (i == 0) {   // zero top row
        for (int j = lane; j < IW; j += 64) Ib[j] = 0.0f;
        return;
    }
    int yy = i - 1 - RN;
    yy = yy < 0 ? 0 : (yy > HN - 1 ? HN - 1 : yy);
    const float* xr = x + b * HN * WN + yy * WN;

    float carry = 0.0f;
#pragma unroll
    for (int c = 0; c < 4; ++c) {           // 4*64 = 256 >= 231
        const int j = c * 64 + lane;
        float v = 0.0f;
        if (j >= 1 && j < IW) {
            int xx = j - 1 - RN;
            xx = xx < 0 ? 0 : (xx > WN - 1 ? WN - 1 : xx);
            v = xr[xx];
        }
#pragma unroll
        for (int d = 1; d < 64; d <<= 1) {
            float n = __shfl_up(v, d, 64);
            if (lane >= d) v += n;
        }
        v += carry;
        if (j < IW) Ib[j] = v;
        carry = __shfl(v, 63, 64);
    }
}

// Thread per (batch, column); coalesced loads/stores down the rows.
__global__ __launch_bounds__(256) void integral_cols_kernel(float* __restrict__ I)
{
    const int t = blockIdx.x * 256 + threadIdx.x;
    if (t >= BN * IW) return;
    const int b = t / IW, j = t % IW;
    float* Ib = I + b * ISZ;
    float acc = 0.0f;
#pragma unroll 11
    for (int i = 1; i < IW; ++i) {
        acc += Ib[i * IW + j];
        Ib[i * IW + j] = acc;
    }
}

// Precompute BM[r-1][b][y][x] = box-mean of radius r centered at (y,x).
// 6 maps x 200 KB = 1.2 MB; 301K px total (~1% of main's pixel count).
__global__ __launch_bounds__(256) void box_mean_kernel(
    const float* __restrict__ I, float* __restrict__ BM)
{
    const int xt = blockIdx.x;                  // 0..3
    const int zb = blockIdx.z;                  // r_idx*2 + b
    const int r_idx = zb >> 1, b = zb & 1;
    const int rad = r_idx + 1;
    const float inv_area = 1.0f / (float)((2 * rad + 1) * (2 * rad + 1));
    const int x = xt * 64 + threadIdx.x;        // 0..255 (mask x<224 on store)
    const int xc = x < WN ? x : WN - 1;         // keep masked lanes in-bounds
    const int y = blockIdx.y * 4 + threadIdx.y;

    const float* Ib = I + b * ISZ;
    const int y0 = y + RN - rad, y1 = y + RN + rad + 1;
    const int x0 = xc + RN - rad, x1 = xc + RN + rad + 1;
    const float* rlo = Ib + y0 * IW;
    const float* rhi = Ib + y1 * IW;
    const float s = rhi[x1] - rlo[x1] - rhi[x0] + rlo[x0];
    if (x < WN)
        BM[(size_t)zb * NPIX + y * WN + x] = s * inv_area;
}

// Main: out(b,p,y,x) = BM_r[b][cy1][cx1] - BM_r[b][cy2][cx2] - t.
// Block (64,4): lanes = 64-wide x-tile; wave loops over 28 rows (y-step 4).
// Per 64-px row: 2 coalesced gathers (wave-uniform row base via readfirstlane,
// per-lane column offset precomputed once), 1 sub, 1 store.
__global__ __launch_bounds__(256) void bad_main_kernel(
    const float* __restrict__ BM,
    const float* __restrict__ ox1, const float* __restrict__ ox2,
    const float* __restrict__ oy1, const float* __restrict__ oy2,
    const int*   __restrict__ radii, const float* __restrict__ thr,
    float* __restrict__ out)
{
    const int p  = blockIdx.y;
    const int b  = blockIdx.z;
    const int xt = blockIdx.x & 3;              // 4 x-tiles of 64 (tile 3 part-masked)
    const int yt = blockIdx.x >> 2;             // 2 y-halves of 112 rows
    const int x  = xt * 64 + threadIdx.x;       // threadIdx.x in 0..63
    const int y0 = yt * (HN / 2) + threadIdx.y; // wave-uniform start row

    // block-uniform descriptor params -> scalar loads
    const float offx1 = ox1[p], offx2 = ox2[p];
    const float offy1 = oy1[p], offy2 = oy2[p];
    const int   rad   = radii[p];
    const float t     = thr[p];

    const float* map = BM + (size_t)((rad - 1) * BN + b) * NPIX;

    // per-lane column indices, computed once (clamp keeps masked lanes in-bounds)
    const float fx = (float)x;
    const int vx1 = (int)fminf(fmaxf(fx + offx1, 0.0f), (float)(WN - 1));
    const int vx2 = (int)fminf(fmaxf(fx + offx2, 0.0f), (float)(WN - 1));

    const bool xok = (x < WN);
    float* outp = out + (size_t)(b * PN + p) * NPIX + (size_t)y0 * WN;

#pragma unroll 4
    for (int i = 0; i < HN / 2; i += 4) {
        const float fy = (float)(y0 + i);
        const int cy1 = __builtin_amdgcn_readfirstlane(
                            (int)fminf(fmaxf(fy + offy1, 0.0f), (float)(HN - 1)));
        const int cy2 = __builtin_amdgcn_readfirstlane(
                            (int)fminf(fmaxf(fy + offy2, 0.0f), (float)(HN - 1)));
        const float v1 = map[cy1 * WN + vx1];
        const float v2 = map[cy2 * WN + vx2];
        if (xok) outp[i * WN + x] = v1 - v2 - t;
    }
}

extern "C" void kernel_launch(void* const* d_in, const int* in_sizes, int n_in,
                              void* d_out, int out_size, void* d_ws, size_t ws_size,
                              hipStream_t stream)
{
    const float* x    = (const float*)d_in[0];
    const float* ox1  = (const float*)d_in[1];
    const float* ox2  = (const float*)d_in[2];
    const float* oy1  = (const float*)d_in[3];
    const float* oy2  = (const float*)d_in[4];
    const int*   rad  = (const int*)d_in[5];
    const float* thr  = (const float*)d_in[6];

    float* I  = (float*)d_ws;                 // BN*ISZ floats = ~427 KB
    float* BM = I + BN * ISZ;                 // 6 * NPIX floats = ~1.2 MB
    float* out = (float*)d_out;

    hipLaunchKernelGGL(integral_rows_kernel, dim3((BN * IW * 64 + 255) / 256), dim3(256), 0, stream, x, I);
    hipLaunchKernelGGL(integral_cols_kernel, dim3((BN * IW + 255) / 256), dim3(256), 0, stream, I);
    hipLaunchKernelGGL(box_mean_kernel,      dim3(4, HN / 4, 6), dim3(64, 4, 1), 0, stream, I, BM);
    hipLaunchKernelGGL(bad_main_kernel,      dim3(8, PN, BN), dim3(64, 4, 1), 0, stream,
                       BM, ox1, ox2, oy1, oy2, rad, thr, out);
}

// Round 6
// 133.902 us; speedup vs baseline: 1.4024x; 1.1090x over previous
//
#include <hip/hip_runtime.h>

// BAD descriptor: direct per-radius box-mean maps + 2-gather main kernel.
// B=2, H=W=224, P=256, max_radius=3, radii in {1,2,3}.
#define BN 2
#define HN 224
#define WN 224
#define PN 256
#define NPIX (HN * WN)  // 50176

// Direct clamped (2r+1)^2-tap box sum. x is L1/L2-resident (200 KB/batch);
// every tap is a lane-contiguous wave-load. Cheaper end-to-end than the
// integral-image pipeline (which cost 2 extra dispatches + an 8-wave serial
// column scan).
template<int RAD>
__device__ __forceinline__ float box_sum(const float* __restrict__ xb, int y, int xc)
{
    int xs[2 * RAD + 1];
#pragma unroll
    for (int dx = -RAD; dx <= RAD; ++dx) {
        int xx = xc + dx;
        xs[dx + RAD] = xx < 0 ? 0 : (xx > WN - 1 ? WN - 1 : xx);
    }
    float s = 0.0f;
#pragma unroll
    for (int dy = -RAD; dy <= RAD; ++dy) {
        int yy = y + dy;
        yy = yy < 0 ? 0 : (yy > HN - 1 ? HN - 1 : yy);
        const float* row = xb + yy * WN;
#pragma unroll
        for (int k = 0; k < 2 * RAD + 1; ++k) s += row[xs[k]];
    }
    return s;
}

// BM[r-1][b][y][x] = mean of x[clamp(y+dy)][clamp(x+dx)], dy,dx in [-r,r].
// 6 maps x 200 KB = 1.2 MB in d_ws.
__global__ __launch_bounds__(256) void box_mean_direct_kernel(
    const float* __restrict__ x, float* __restrict__ BM)
{
    const int zb = blockIdx.z;                 // r_idx*2 + b
    const int r_idx = zb >> 1, b = zb & 1;
    const int xi = blockIdx.x * 64 + threadIdx.x;   // 0..255 (mask xi<224 on store)
    const int y  = blockIdx.y * 4 + threadIdx.y;
    const int xc = xi < WN ? xi : WN - 1;           // keep masked lanes in-bounds

    const float* xb = x + b * NPIX;
    float s;
    if (r_idx == 0)      s = box_sum<1>(xb, y, xc) * (1.0f / 9.0f);
    else if (r_idx == 1) s = box_sum<2>(xb, y, xc) * (1.0f / 25.0f);
    else                 s = box_sum<3>(xb, y, xc) * (1.0f / 49.0f);

    if (xi < WN)
        BM[(size_t)zb * NPIX + y * WN + xi] = s;
}

// Main: out(b,p,y,x) = BM_r[b][cy1][cx1] - BM_r[b][cy2][cx2] - t.
// Block (64,4): lanes = 64-wide x-tile; wave loops over 28 rows (y-step 4).
// Per 64-px row: 2 gathers (wave-uniform row base via readfirstlane, per-lane
// column offset precomputed once), 1 sub, 1 coalesced store.
__global__ __launch_bounds__(256) void bad_main_kernel(
    const float* __restrict__ BM,
    const float* __restrict__ ox1, const float* __restrict__ ox2,
    const float* __restrict__ oy1, const float* __restrict__ oy2,
    const int*   __restrict__ radii, const float* __restrict__ thr,
    float* __restrict__ out)
{
    const int p  = blockIdx.y;
    const int b  = blockIdx.z;
    const int xt = blockIdx.x & 3;              // 4 x-tiles of 64 (tile 3 part-masked)
    const int yt = blockIdx.x >> 2;             // 2 y-halves of 112 rows
    const int x  = xt * 64 + threadIdx.x;       // threadIdx.x in 0..63
    const int y0 = yt * (HN / 2) + threadIdx.y; // wave-uniform start row

    // block-uniform descriptor params -> scalar loads
    const float offx1 = ox1[p], offx2 = ox2[p];
    const float offy1 = oy1[p], offy2 = oy2[p];
    const int   rad   = radii[p];
    const float t     = thr[p];

    const float* map = BM + (size_t)((rad - 1) * BN + b) * NPIX;

    // per-lane column indices, computed once (clamp keeps masked lanes in-bounds)
    const float fx = (float)x;
    const int vx1 = (int)fminf(fmaxf(fx + offx1, 0.0f), (float)(WN - 1));
    const int vx2 = (int)fminf(fmaxf(fx + offx2, 0.0f), (float)(WN - 1));

    const bool xok = (x < WN);
    float* outp = out + (size_t)(b * PN + p) * NPIX + (size_t)y0 * WN;

#pragma unroll 4
    for (int i = 0; i < HN / 2; i += 4) {
        const float fy = (float)(y0 + i);
        const int cy1 = __builtin_amdgcn_readfirstlane(
                            (int)fminf(fmaxf(fy + offy1, 0.0f), (float)(HN - 1)));
        const int cy2 = __builtin_amdgcn_readfirstlane(
                            (int)fminf(fmaxf(fy + offy2, 0.0f), (float)(HN - 1)));
        const float v1 = map[cy1 * WN + vx1];
        const float v2 = map[cy2 * WN + vx2];
        if (xok) outp[i * WN + x] = v1 - v2 - t;
    }
}

extern "C" void kernel_launch(void* const* d_in, const int* in_sizes, int n_in,
                              void* d_out, int out_size, void* d_ws, size_t ws_size,
                              hipStream_t stream)
{
    const float* x    = (const float*)d_in[0];
    const float* ox1  = (const float*)d_in[1];
    const float* ox2  = (const float*)d_in[2];
    const float* oy1  = (const float*)d_in[3];
    const float* oy2  = (const float*)d_in[4];
    const int*   rad  = (const int*)d_in[5];
    const float* thr  = (const float*)d_in[6];

    float* BM  = (float*)d_ws;                // 6 * NPIX floats = ~1.2 MB
    float* out = (float*)d_out;

    hipLaunchKernelGGL(box_mean_direct_kernel, dim3(4, HN / 4, 6), dim3(64, 4, 1), 0, stream, x, BM);
    hipLaunchKernelGGL(bad_main_kernel,        dim3(8, PN, BN), dim3(64, 4, 1), 0, stream,
                       BM, ox1, ox2, oy1, oy2, rad, thr, out);
}